// Round 16
// baseline (229.318 us; speedup 1.0000x reference)
//
#include <hip/hip_runtime.h>
#include <math.h>

#define B_    4
#define CIN_  32
#define COUT_ 64
#define H_    192
#define W_    192
#define HW_   (H_ * W_)        // 36864
#define NPIX_ (B_ * HW_)       // 147456
#define EPS_  1e-5f

// XCD-aware swizzle (proven R7): XCD k owns a contiguous half-image-plane.
static __device__ __forceinline__ int swz2304(int blk) {
    return ((blk & 7) * 288) + (blk >> 3);
}

struct Cr { int o00, o01, o10, o11; float w00, w01, w10, w11; };

// packed fp32 (v_pk_fma_f32 on gfx950): 2 FMA / instruction
using v2f = __attribute__((ext_vector_type(2))) float;
static __device__ __forceinline__ v2f vfma(v2f a, v2f b, v2f c) {
    return __builtin_elementwise_fma(a, b, c);
}

// ---------------------------------------------------------------------------
// Kernel 0: fused prep (unchanged from R15).
// Blocks [0,576): transpose x (NCHW) -> xt (NHWC) via LDS staging.
// Blocks [576,673): weight transposes + stats zeroing.
// wt_def[kk][c][o64]; wt_off [kk][o20][c32] (o>=18 zero).
// ---------------------------------------------------------------------------
__global__ __launch_bounds__(256) void k_pre(
    const float* __restrict__ x, const float* __restrict__ w_def,
    const float* __restrict__ w_off, float* __restrict__ xt,
    float* __restrict__ wt_def, float* __restrict__ wt_off,
    float* __restrict__ stats)
{
    if (blockIdx.x < NPIX_ / 256) {
        __shared__ float lds[32 * 257];
        const int tid  = threadIdx.x;
        const int pid0 = blockIdx.x * 256;
        const int b    = pid0 / HW_;
        const int rem0 = pid0 - b * HW_;
        const float* xb = x + (size_t)b * CIN_ * HW_ + rem0;

#pragma unroll
        for (int c = 0; c < 32; ++c)
            lds[c * 257 + tid] = xb[c * HW_ + tid];
        __syncthreads();

        float4* dst = (float4*)(xt + (size_t)pid0 * 32);
#pragma unroll
        for (int i = 0; i < 8; ++i) {
            const int idx = i * 256 + tid;
            const int px  = idx >> 3;
            const int q   = idx & 7;
            float4 v;
            v.x = lds[(q * 4 + 0) * 257 + px];
            v.y = lds[(q * 4 + 1) * 257 + px];
            v.z = lds[(q * 4 + 2) * 257 + px];
            v.w = lds[(q * 4 + 3) * 257 + px];
            dst[idx] = v;
        }
    } else {
        const int i = (blockIdx.x - NPIX_ / 256) * 256 + threadIdx.x;
        if (i < 18432) {                       // wt_def[kk][c][o64]
            const int o  = i & 63;
            const int c  = (i >> 6) & 31;
            const int kk = i >> 11;
            wt_def[i] = w_def[(o * 32 + c) * 9 + kk];
        } else if (i < 18432 + 5760) {         // wt_off[kk][o20][c32]
            const int e  = i - 18432;
            const int c  = e & 31;
            const int t  = e >> 5;
            const int o  = t % 20;
            const int kk = t / 20;
            wt_off[e] = (o < 18) ? w_off[(o * 32 + c) * 9 + kk] : 0.f;
        } else if (i < 18432 + 5760 + 512) {
            stats[i - 18432 - 5760] = 0.f;     // sum_bc + sumsq_bc
        }
    }
}

// ---------------------------------------------------------------------------
// Kernel 1: FUSED offsets-conv + deformable conv + BN stats.
// R14/R15 structure; FMA-dense loops rewritten over float2 ext-vectors so
// the backend emits v_pk_fma_f32 (2 FMA/instr): phase-2 4608->2304 instr,
// stage-A 1440->~800, bilinear 288->144.
// ---------------------------------------------------------------------------
__global__ __launch_bounds__(256, 6) void k_fused(
    const float* __restrict__ xt, const float* __restrict__ wto,
    const float* __restrict__ b_off, const float* __restrict__ wtd,
    const float* __restrict__ b_def, float* __restrict__ y,
    float* __restrict__ sum_bc, float* __restrict__ sumsq_bc)
{
    __shared__ __align__(16) float smem[6336];   // 25,344 B: tile, then vbuf
    __shared__ float offlds[20 * 64];            // 5 KB
    float4 (*tile)[198] = (float4(*)[198])smem;  // [ch-quad j][r*66+cc]
    float* vbuf = smem;                          // [2][32][64] after stage A

    const int tid  = threadIdx.x;
    const int px   = tid & 63;
    const int og   = __builtin_amdgcn_readfirstlane(tid >> 6);  // uniform
    const int lane = tid & 63;                   // == px

    const int blk  = swz2304(blockIdx.x);
    const int base = blk * 64;
    const int b    = base / HW_;
    const int rem0 = base - b * HW_;
    const int h0   = rem0 / W_;
    const int w0   = rem0 - h0 * W_;             // 0, 64, or 128
    const float* xb = xt + (size_t)b * HW_ * 32;

    // ---------------- Stage A: offsets conv (packed f32) ----------------
    for (int i = tid; i < 1584; i += 256) {
        const int j   = i & 7;
        const int rec = i >> 3;
        const int r   = rec / 66;
        const int cc  = rec - r * 66;
        const int hc  = min(max(h0 + r - 1, 0), H_ - 1);
        const int wc  = min(max(w0 + cc - 1, 0), W_ - 1);
        tile[j][rec] = *(const float4*)(xb + (hc * W_ + wc) * 32 + j * 4);
    }
    __syncthreads();

    {
        const bool rv0 = (h0 - 1 >= 0), rv2 = (h0 + 1 < H_);
        v2f acc5v[5];
#pragma unroll
        for (int oo = 0; oo < 5; ++oo) acc5v[oo] = (v2f){0.f, 0.f};

#pragma unroll 1
        for (int kk = 0; kk < 9; ++kk) {
            const int ky = kk / 3, kx = kk % 3;
            const bool rok = (ky == 0) ? rv0 : ((ky == 2) ? rv2 : true);
            const int wcol = w0 + px + kx - 1;
            const float g = (rok && wcol >= 0 && wcol < W_) ? 1.f : 0.f;
            const int rec = ky * 66 + px + kx;
            const v2f gv = (v2f){g, g};

            v2f xv[16];
#pragma unroll
            for (int j = 0; j < 8; ++j) {
                const float4 t4 = tile[j][rec];
                xv[2 * j + 0] = (v2f){t4.x, t4.y} * gv;
                xv[2 * j + 1] = (v2f){t4.z, t4.w} * gv;
            }
            const float* wk = wto + (kk * 20 + og * 5) * 32;
#pragma unroll
            for (int oo = 0; oo < 5; ++oo) {
                const v2f* wr2 = (const v2f*)(wk + oo * 32);
                v2f s = acc5v[oo];
#pragma unroll
                for (int m = 0; m < 16; ++m) s = vfma(xv[m], wr2[m], s);
                acc5v[oo] = s;
            }
        }
#pragma unroll
        for (int oo = 0; oo < 5; ++oo) {
            const int o = og * 5 + oo;
            if (o < 18)
                offlds[o * 64 + px] = acc5v[oo][0] + acc5v[oo][1] + b_off[o];
        }
    }
    __syncthreads();          // tile dead; offlds ready; vbuf region free

    // ---------------- Stage B: deformable conv ----------------
    const int h = h0;
    const int w = w0 + px;
    const float* xg = xb + og * 8;               // channels [8og, 8og+8)

    v2f acc2[8];
#pragma unroll
    for (int q = 0; q < 8; ++q) acc2[q] = (v2f){0.f, 0.f};

    auto mk = [&](int kk) -> Cr {
        const float dy = offlds[(2 * kk) * 64 + px];
        const float dx = offlds[(2 * kk + 1) * 64 + px];
        const float py = (float)(h + kk / 3 - 1) + dy;
        const float qx = (float)(w + kk % 3 - 1) + dx;
        const float y0f = floorf(py), x0f = floorf(qx);
        const float wy = py - y0f, wx = qx - x0f;
        const int iy0 = (int)y0f, ix0 = (int)x0f;
        const int iy1 = iy0 + 1,  ix1 = ix0 + 1;
        const float vy0 = (iy0 >= 0 && iy0 < H_) ? 1.f : 0.f;
        const float vy1 = (iy1 >= 0 && iy1 < H_) ? 1.f : 0.f;
        const float vx0 = (ix0 >= 0 && ix0 < W_) ? 1.f : 0.f;
        const float vx1 = (ix1 >= 0 && ix1 < W_) ? 1.f : 0.f;
        Cr c;
        c.w00 = (1.f - wy) * (1.f - wx) * vy0 * vx0;
        c.w01 = (1.f - wy) * wx * vy0 * vx1;
        c.w10 = wy * (1.f - wx) * vy1 * vx0;
        c.w11 = wy * wx * vy1 * vx1;
        const int cy0 = min(max(iy0, 0), H_ - 1), cy1 = min(max(iy1, 0), H_ - 1);
        const int cx0 = min(max(ix0, 0), W_ - 1), cx1 = min(max(ix1, 0), W_ - 1);
        c.o00 = (cy0 * W_ + cx0) * 32; c.o01 = (cy0 * W_ + cx1) * 32;
        c.o10 = (cy1 * W_ + cx0) * 32; c.o11 = (cy1 * W_ + cx1) * 32;
        return c;
    };

    // packed bilinear: 4 corner float4-pairs -> v[8] (as 4 v2f)
    auto bil = [](const Cr& c, const float4& A0, const float4& A1,
                  const float4& B0, const float4& B1,
                  const float4& C0, const float4& C1,
                  const float4& D0, const float4& D1, v2f* p) {
        const v2f w00v = (v2f){c.w00, c.w00}, w01v = (v2f){c.w01, c.w01};
        const v2f w10v = (v2f){c.w10, c.w10}, w11v = (v2f){c.w11, c.w11};
        p[0] = vfma((v2f){D0.x, D0.y}, w11v,
               vfma((v2f){C0.x, C0.y}, w10v,
               vfma((v2f){B0.x, B0.y}, w01v, (v2f){A0.x, A0.y} * w00v)));
        p[1] = vfma((v2f){D0.z, D0.w}, w11v,
               vfma((v2f){C0.z, C0.w}, w10v,
               vfma((v2f){B0.z, B0.w}, w01v, (v2f){A0.z, A0.w} * w00v)));
        p[2] = vfma((v2f){D1.x, D1.y}, w11v,
               vfma((v2f){C1.x, C1.y}, w10v,
               vfma((v2f){B1.x, B1.y}, w01v, (v2f){A1.x, A1.y} * w00v)));
        p[3] = vfma((v2f){D1.z, D1.w}, w11v,
               vfma((v2f){C1.z, C1.w}, w10v,
               vfma((v2f){B1.z, B1.w}, w01v, (v2f){A1.z, A1.w} * w00v)));
    };

    // prologue: corners(0) -> v(0) -> vbuf[0]
    {
        Cr c0 = mk(0);
        float4 A0 = *(const float4*)(xg + c0.o00), A1 = *(const float4*)(xg + c0.o00 + 4);
        float4 B0 = *(const float4*)(xg + c0.o01), B1 = *(const float4*)(xg + c0.o01 + 4);
        float4 C0 = *(const float4*)(xg + c0.o10), C1 = *(const float4*)(xg + c0.o10 + 4);
        float4 D0 = *(const float4*)(xg + c0.o11), D1 = *(const float4*)(xg + c0.o11 + 4);
        v2f p[4];
        bil(c0, A0, A1, B0, B1, C0, C1, D0, D1, p);
#pragma unroll
        for (int j = 0; j < 8; ++j)
            vbuf[(og * 8 + j) * 64 + px] = p[j >> 1][j & 1];
    }
    __syncthreads();

#pragma unroll 1
    for (int kk = 0; kk < 9; ++kk) {
        // issue next kk's gathers now — they fly during phase 2
        Cr nx; float4 A0, A1, B0, B1, C0, C1, D0, D1;
        if (kk < 8) {
            nx = mk(kk + 1);
            A0 = *(const float4*)(xg + nx.o00); A1 = *(const float4*)(xg + nx.o00 + 4);
            B0 = *(const float4*)(xg + nx.o01); B1 = *(const float4*)(xg + nx.o01 + 4);
            C0 = *(const float4*)(xg + nx.o10); C1 = *(const float4*)(xg + nx.o10 + 4);
            D0 = *(const float4*)(xg + nx.o11); D1 = *(const float4*)(xg + nx.o11 + 4);
        }

        // phase 2: 16 outputs from vbuf[kk&1] — packed FMA (8/channel)
        const float* vp = vbuf + (kk & 1) * 2048;
        const float* wk = wtd + (kk << 11) + (og << 4);   // wt[kk][.][16og]
#pragma unroll 8
        for (int c = 0; c < 32; ++c) {
            const float vvs = vp[c * 64 + px];
            const v2f vv = (v2f){vvs, vvs};
            const v2f* wr2 = (const v2f*)(wk + (c << 6));
            acc2[0] = vfma(vv, wr2[0], acc2[0]);
            acc2[1] = vfma(vv, wr2[1], acc2[1]);
            acc2[2] = vfma(vv, wr2[2], acc2[2]);
            acc2[3] = vfma(vv, wr2[3], acc2[3]);
            acc2[4] = vfma(vv, wr2[4], acc2[4]);
            acc2[5] = vfma(vv, wr2[5], acc2[5]);
            acc2[6] = vfma(vv, wr2[6], acc2[6]);
            acc2[7] = vfma(vv, wr2[7], acc2[7]);
        }

        if (kk < 8) {                      // bilinear(kk+1) -> other buffer
            v2f p[4];
            bil(nx, A0, A1, B0, B1, C0, C1, D0, D1, p);
            float* wp = vbuf + ((kk + 1) & 1) * 2048;
#pragma unroll
            for (int j = 0; j < 8; ++j)
                wp[(og * 8 + j) * 64 + px] = p[j >> 1][j & 1];
            __syncthreads();               // vbuf[(kk+1)&1] ready; reads of
        }                                  // vbuf[kk&1] done before rewrite
    }

    // bias + store (16 channels for this og)
    const int rem = rem0 + px;
    float* yp = y + ((size_t)b * COUT_ + og * 16) * HW_ + rem;
    float fin[16];
#pragma unroll
    for (int q = 0; q < 16; ++q) {
        fin[q] = acc2[q >> 1][q & 1] + b_def[og * 16 + q];
        yp[q * HW_] = fin[q];
    }

    // fused BN stats: wave = (64 px, one og). Butterfly 16 channels.
    float ls = 0.f, lq = 0.f;
#pragma unroll
    for (int o = 0; o < 16; ++o) {
        float t = fin[o];
        float u = t * t;
#pragma unroll
        for (int s = 32; s; s >>= 1) {
            t += __shfl_xor(t, s, 64);
            u += __shfl_xor(u, s, 64);
        }
        if (lane == o) { ls = t; lq = u; }
    }
    if (lane < 16) {
        atomicAdd(&sum_bc[b * 64 + og * 16 + lane], ls);
        atomicAdd(&sumsq_bc[b * 64 + og * 16 + lane], lq);
    }
}

// ---------------------------------------------------------------------------
// Kernel 2: fused SE-MLP + affine(BN*SE) + ReLU + 2x2 maxpool (unchanged).
// ---------------------------------------------------------------------------
__global__ __launch_bounds__(256) void k_finish(
    const float* __restrict__ y,
    const float* __restrict__ sum_bc, const float* __restrict__ sumsq_bc,
    const float* __restrict__ gamma, const float* __restrict__ beta,
    const float* __restrict__ fc1_w, const float* __restrict__ fc1_b,
    const float* __restrict__ fc2_w, const float* __restrict__ fc2_b,
    float* __restrict__ out)
{
    __shared__ float sal[256], sbb[256], sin_[256];
    const int tid = threadIdx.x;
    {
        const int b = tid >> 6, c = tid & 63;
        float ch_s = 0.f, ch_q = 0.f;
#pragma unroll
        for (int bb = 0; bb < 4; ++bb) {
            ch_s += sum_bc[bb * 64 + c];
            ch_q += sumsq_bc[bb * 64 + c];
        }
        const float invN = 1.f / (float)(B_ * HW_);
        const float mean = ch_s * invN;
        const float var  = ch_q * invN - mean * mean;
        const float a    = gamma[c] * rsqrtf(var + EPS_);
        const float bi   = beta[c] - mean * a;
        sin_[tid] = a * (sum_bc[tid] * (1.f / (float)HW_)) + bi;
        __syncthreads();
        float hv[4];
#pragma unroll
        for (int j = 0; j < 4; ++j) {
            float hs = fc1_b[j];
            for (int cc = 0; cc < 64; ++cc)
                hs += sin_[b * 64 + cc] * fc1_w[j * 64 + cc];
            hv[j] = fmaxf(hs, 0.f);
        }
        float o = fc2_b[c];
#pragma unroll
        for (int j = 0; j < 4; ++j) o += hv[j] * fc2_w[c * 4 + j];
        const float s = 1.f / (1.f + expf(-o));
        sal[tid] = a * s;
        sbb[tid] = bi * s;
    }
    __syncthreads();

    const int t    = blockIdx.x * 256 + tid;
    const int opix = t * 2;
    const int bc   = opix / (96 * 96);
    const int rem  = opix - bc * (96 * 96);
    const int oh   = rem / 96, ow = rem - oh * 96;   // ow even
    const float al = sal[bc], bb = sbb[bc];
    const float* yp = y + (size_t)bc * HW_ + (2 * oh) * W_ + 2 * ow;
    const float4 r0 = *(const float4*)yp;
    const float4 r1 = *(const float4*)(yp + W_);
    float2 st;
    st.x = fmaxf(fmaxf(fmaxf(fmaf(r0.x, al, bb), fmaf(r0.y, al, bb)),
                       fmaxf(fmaf(r1.x, al, bb), fmaf(r1.y, al, bb))), 0.f);
    st.y = fmaxf(fmaxf(fmaxf(fmaf(r0.z, al, bb), fmaf(r0.w, al, bb)),
                       fmaxf(fmaf(r1.z, al, bb), fmaf(r1.w, al, bb))), 0.f);
    *(float2*)(out + opix) = st;
}

// ---------------------------------------------------------------------------
extern "C" void kernel_launch(void* const* d_in, const int* in_sizes, int n_in,
                              void* d_out, int out_size, void* d_ws, size_t ws_size,
                              hipStream_t stream)
{
    const float* x     = (const float*)d_in[0];
    const float* w_off = (const float*)d_in[1];
    const float* b_off = (const float*)d_in[2];
    const float* w_def = (const float*)d_in[3];
    const float* b_def = (const float*)d_in[4];
    const float* gamma = (const float*)d_in[5];
    const float* beta  = (const float*)d_in[6];
    const float* fc1_w = (const float*)d_in[7];
    const float* fc1_b = (const float*)d_in[8];
    const float* fc2_w = (const float*)d_in[9];
    const float* fc2_b = (const float*)d_in[10];
    float* out = (float*)d_out;

    float* ws   = (float*)d_ws;
    float* yb     = ws;                          // 9,437,184 floats
    float* xt     = yb + 9437184;                // 4,718,592 floats (NHWC x)
    float* wt_def = xt + 4718592;                // 18,432
    float* wt_off = wt_def + 18432;              // 5,760
    float* stats  = wt_off + 5760;               // 1,024
    float* sum_bc   = stats;
    float* sumsq_bc = stats + 256;

    k_pre   <<<dim3(NPIX_ / 256 + 97), dim3(256), 0, stream>>>(
                x, w_def, w_off, xt, wt_def, wt_off, stats);
    k_fused <<<dim3(NPIX_ / 64), dim3(256), 0, stream>>>(
                xt, wt_off, b_off, wt_def, b_def, yb, sum_bc, sumsq_bc);
    k_finish<<<dim3(B_ * COUT_ * 96 * 96 / 512), dim3(256), 0, stream>>>(
                yb, sum_bc, sumsq_bc, gamma, beta,
                fc1_w, fc1_b, fc2_w, fc2_b, out);
}